// Round 1
// baseline (92.001 us; speedup 1.0000x reference)
//
#include <hip/hip_runtime.h>
#include <math.h>

namespace {
constexpr int D_     = 8192;   // stream width (N*D)
constexpr int NROWS  = 8192;   // B*S
constexpr int RPB    = 16;     // rows per block
constexpr int T      = 512;    // threads per block (16 rows x 32 lanes)
constexpr int CHUNK  = 512;    // K-chunk staged in LDS
constexpr int NCHUNK = D_ / CHUNK;   // 16
constexpr int P      = 28;     // padded floats per position in LDS (24 used)
constexpr int OFF_POST = NROWS * 4;  // 32768
constexpr int OFF_RES  = NROWS * 8;  // 65536
}

__global__ __launch_bounds__(T, 4)
void mhc_fused(const float* __restrict__ x,
               const float* __restrict__ phi_pre,
               const float* __restrict__ phi_post,
               const float* __restrict__ phi_res,
               const float* __restrict__ alpha_pre_p,
               const float* __restrict__ alpha_post_p,
               const float* __restrict__ alpha_res_p,
               const float* __restrict__ b_pre,
               const float* __restrict__ b_post,
               const float* __restrict__ b_res,
               float* __restrict__ out)
{
    __shared__ float lds[CHUNK * P];   // 57344 B -> 2 blocks/CU
    const int t    = (int)threadIdx.x;
    const int lane = t & 31;
    const int row  = (int)blockIdx.x * RPB + (t >> 5);
    const float* __restrict__ xrow = x + (size_t)row * D_;

    float ap[4]  = {0.f, 0.f, 0.f, 0.f};
    float ao[4]  = {0.f, 0.f, 0.f, 0.f};
    float ar[16] = {0.f, 0.f, 0.f, 0.f, 0.f, 0.f, 0.f, 0.f,
                    0.f, 0.f, 0.f, 0.f, 0.f, 0.f, 0.f, 0.f};
    float ssq = 0.f, mxq = 0.f;

    for (int ch = 0; ch < NCHUNK; ++ch) {
        const int k0 = ch * CHUNK;
        __syncthreads();   // previous chunk's readers done before overwrite
        // ---- stage phi chunk into LDS (all loads perfectly coalesced) ----
        {
            const float4 vp = *(const float4*)(phi_pre  + (size_t)(k0 + t) * 4);
            const float4 vq = *(const float4*)(phi_post + (size_t)(k0 + t) * 4);
            *(float4*)&lds[t * P + 0] = vp;
            *(float4*)&lds[t * P + 4] = vq;
#pragma unroll
            for (int i = 0; i < 4; ++i) {
                const int l   = i * T + t;        // 0..2047 consecutive
                const int pos = l >> 2;
                const int j   = l & 3;
                const float4 vr = *(const float4*)(phi_res + (size_t)(k0 + pos) * 16 + j * 4);
                *(float4*)&lds[pos * P + 8 + j * 4] = vr;
            }
        }
        // ---- x loads for this chunk (independent of LDS; overlap staging) ----
        float xv[16];
#pragma unroll
        for (int u = 0; u < 16; ++u)
            xv[u] = xrow[k0 + u * 32 + lane];
        __syncthreads();
        // ---- accumulate 24 dots + sum(x^2) + max(x^2) ----
#pragma unroll
        for (int u = 0; u < 16; ++u) {
            const float v = xv[u];
            const float* ph = &lds[(u * 32 + lane) * P];
            ssq = fmaf(v, v, ssq);
            mxq = fmaxf(mxq, v * v);
            const float4 p0 = *(const float4*)(ph + 0);
            const float4 p1 = *(const float4*)(ph + 4);
            ap[0] = fmaf(v, p0.x, ap[0]); ap[1] = fmaf(v, p0.y, ap[1]);
            ap[2] = fmaf(v, p0.z, ap[2]); ap[3] = fmaf(v, p0.w, ap[3]);
            ao[0] = fmaf(v, p1.x, ao[0]); ao[1] = fmaf(v, p1.y, ao[1]);
            ao[2] = fmaf(v, p1.z, ao[2]); ao[3] = fmaf(v, p1.w, ao[3]);
#pragma unroll
            for (int j2 = 0; j2 < 4; ++j2) {
                const float4 pr = *(const float4*)(ph + 8 + 4 * j2);
                ar[4*j2+0] = fmaf(v, pr.x, ar[4*j2+0]);
                ar[4*j2+1] = fmaf(v, pr.y, ar[4*j2+1]);
                ar[4*j2+2] = fmaf(v, pr.z, ar[4*j2+2]);
                ar[4*j2+3] = fmaf(v, pr.w, ar[4*j2+3]);
            }
        }
    }

    // ---- per-row reduction across 32 lanes via reused LDS ----
    __syncthreads();
#pragma unroll
    for (int m = 1; m <= 16; m <<= 1)
        mxq = fmaxf(mxq, __shfl_xor(mxq, m));

    float* red = lds;
    {
        const int b = t * 25;
#pragma unroll
        for (int c = 0; c < 4; ++c)  red[b + c]     = ap[c];
#pragma unroll
        for (int c = 0; c < 4; ++c)  red[b + 4 + c] = ao[c];
#pragma unroll
        for (int c = 0; c < 16; ++c) red[b + 8 + c] = ar[c];
        red[b + 24] = ssq;
    }
    __syncthreads();
    const int rowbase25 = (t & ~31) * 25;
    float redv = 0.f;
    if (lane < 25) {
#pragma unroll
        for (int s = 0; s < 32; ++s)
            redv += red[rowbase25 + s * 25 + lane];
    }
    const float ssq_tot = __shfl(redv, 24, 32);
    const float msq  = ssq_tot * (1.f / 8192.f) + 1e-6f;   // rms^2 (incl. eps)
    const float rinv = 1.f / sqrtf(msq);

    const float a_pre  = alpha_pre_p[0];
    const float a_post = alpha_post_p[0];
    const float a_res  = alpha_res_p[0];

    const bool needclamp = (mxq > 100.f * msq);   // |x|/rms > 10 somewhere?

    if (!needclamp) {
        // lane v (<25) holds reduced value v: 0..3 pre, 4..7 post, 8..23 res, 24 ssq
        const int e = lane & 15;                      // res element i*4+j
        float m = __shfl(redv, 8 + e, 32);
        m = a_res * m * rinv + b_res[e];
        m = fminf(fmaxf(m, -20.f), 20.f);
        m = expf(m);
        for (int it = 0; it < 20; ++it) {
            float rs = m + __shfl_xor(m, 1);          // sum over j (axis -1)
            rs += __shfl_xor(rs, 2);
            m = m / (rs + 1e-6f);
            float cs = m + __shfl_xor(m, 4);          // sum over i (axis -2)
            cs += __shfl_xor(cs, 8);
            m = m / (cs + 1e-6f);
        }
        if (lane < 16)
            out[OFF_RES + (size_t)row * 16 + lane] = m;
        if (lane < 4) {
            const float h = a_pre * redv * rinv + b_pre[lane];
            out[(size_t)row * 4 + lane] = 1.f / (1.f + expf(-h));
        } else if (lane < 8) {
            const float h = a_post * redv * rinv + b_post[lane - 4];
            out[OFF_POST + (size_t)row * 4 + (lane - 4)] = 2.f / (1.f + expf(-h));
        }
    } else if (lane == 0) {
        // exact clamped slow path — semantically required, never expected to run
        float dp[4] = {0.f,0.f,0.f,0.f}, dq[4] = {0.f,0.f,0.f,0.f};
        float dr[16] = {0.f,0.f,0.f,0.f,0.f,0.f,0.f,0.f,
                        0.f,0.f,0.f,0.f,0.f,0.f,0.f,0.f};
        for (int k = 0; k < D_; ++k) {
            float v = xrow[k] * rinv;
            v = fminf(fmaxf(v, -10.f), 10.f);
            const float4 pp = *(const float4*)(phi_pre  + (size_t)k * 4);
            const float4 pq = *(const float4*)(phi_post + (size_t)k * 4);
            dp[0] = fmaf(v, pp.x, dp[0]); dp[1] = fmaf(v, pp.y, dp[1]);
            dp[2] = fmaf(v, pp.z, dp[2]); dp[3] = fmaf(v, pp.w, dp[3]);
            dq[0] = fmaf(v, pq.x, dq[0]); dq[1] = fmaf(v, pq.y, dq[1]);
            dq[2] = fmaf(v, pq.z, dq[2]); dq[3] = fmaf(v, pq.w, dq[3]);
#pragma unroll
            for (int j2 = 0; j2 < 4; ++j2) {
                const float4 pr = *(const float4*)(phi_res + (size_t)k * 16 + 4 * j2);
                dr[4*j2+0] = fmaf(v, pr.x, dr[4*j2+0]);
                dr[4*j2+1] = fmaf(v, pr.y, dr[4*j2+1]);
                dr[4*j2+2] = fmaf(v, pr.z, dr[4*j2+2]);
                dr[4*j2+3] = fmaf(v, pr.w, dr[4*j2+3]);
            }
        }
        float mm[16];
#pragma unroll
        for (int e2 = 0; e2 < 16; ++e2) {
            float m = a_res * dr[e2] + b_res[e2];
            m = fminf(fmaxf(m, -20.f), 20.f);
            mm[e2] = expf(m);
        }
        for (int it = 0; it < 20; ++it) {
#pragma unroll
            for (int i2 = 0; i2 < 4; ++i2) {
                const float rs = mm[i2*4] + mm[i2*4+1] + mm[i2*4+2] + mm[i2*4+3] + 1e-6f;
#pragma unroll
                for (int j2 = 0; j2 < 4; ++j2) mm[i2*4+j2] /= rs;
            }
#pragma unroll
            for (int j2 = 0; j2 < 4; ++j2) {
                const float cs = mm[j2] + mm[4+j2] + mm[8+j2] + mm[12+j2] + 1e-6f;
#pragma unroll
                for (int i2 = 0; i2 < 4; ++i2) mm[i2*4+j2] /= cs;
            }
        }
#pragma unroll
        for (int j = 0; j < 4; ++j) {
            out[(size_t)row * 4 + j]            = 1.f / (1.f + expf(-(a_pre  * dp[j] + b_pre[j])));
            out[OFF_POST + (size_t)row * 4 + j] = 2.f / (1.f + expf(-(a_post * dq[j] + b_post[j])));
        }
#pragma unroll
        for (int e2 = 0; e2 < 16; ++e2)
            out[OFF_RES + (size_t)row * 16 + e2] = mm[e2];
    }
}

extern "C" void kernel_launch(void* const* d_in, const int* in_sizes, int n_in,
                              void* d_out, int out_size, void* d_ws, size_t ws_size,
                              hipStream_t stream)
{
    const float* x        = (const float*)d_in[0];
    const float* phi_pre  = (const float*)d_in[1];
    const float* phi_post = (const float*)d_in[2];
    const float* phi_res  = (const float*)d_in[3];
    const float* a_pre    = (const float*)d_in[4];
    const float* a_post   = (const float*)d_in[5];
    const float* a_res    = (const float*)d_in[6];
    const float* b_pre    = (const float*)d_in[7];
    const float* b_post   = (const float*)d_in[8];
    const float* b_res    = (const float*)d_in[9];
    float* out = (float*)d_out;

    dim3 grid(NROWS / RPB);   // 512
    dim3 block(T);            // 512
    hipLaunchKernelGGL(mhc_fused, grid, block, 0, stream,
                       x, phi_pre, phi_post, phi_res,
                       a_pre, a_post, a_res, b_pre, b_post, b_res, out);
}

// Round 2
// 59.296 us; speedup vs baseline: 1.5516x; 1.5516x over previous
//
#include <hip/hip_runtime.h>
#include <math.h>

typedef __attribute__((ext_vector_type(8))) short bf16x8;   // 8 bf16 = 4 VGPRs
typedef __attribute__((ext_vector_type(4))) float f32x4;

namespace {
constexpr int D_     = 8192;          // stream width (N*D)
constexpr int NROWS  = 8192;          // B*S
constexpr int RPB    = 16;            // rows per block (one M-tile)
constexpr int T      = 512;           // threads per block = 8 waves
constexpr int WAVES  = 8;
constexpr int KSTEPS = D_ / 32;       // 256 global K-steps of 32
constexpr int SPW    = KSTEPS / WAVES;// 32 steps per wave
constexpr int OFF_POST = NROWS * 4;
constexpr int OFF_RES  = NROWS * 8;
constexpr size_t WS_NEED = (size_t)KSTEPS * 2 * 64 * 16;  // 512 KiB of B-fragments

__device__ __forceinline__ short f2bf(float f) {
    union { float f; unsigned u; } c; c.f = f;
    unsigned u = c.u + 0x7fffu + ((c.u >> 16) & 1u);   // RNE (no NaN in data)
    return (short)(u >> 16);
}
}

// ---- prep: Φ (fp32) -> bf16 B-fragments in ws, lane-ordered, N padded to 32 ----
__global__ void prep_bfrag(const float* __restrict__ pre,
                           const float* __restrict__ post,
                           const float* __restrict__ res,
                           uint4* __restrict__ ws)
{
    const int gid  = (int)blockIdx.x * 256 + (int)threadIdx.x;  // 0..32767
    const int lane = gid & 63;
    const int n    = (gid >> 6) & 1;       // fragment half: cols 0-15 / 16-31
    const int s    = gid >> 7;             // global K-step 0..255
    const int g    = lane >> 4;
    const int col  = n * 16 + (lane & 15);
    const int kb   = s * 32 + g * 8;
    unsigned short sv[8];
#pragma unroll
    for (int j = 0; j < 8; ++j) {
        const int k = kb + j;
        float v;
        if      (col < 4)  v = pre [(size_t)k * 4  + col];
        else if (col < 8)  v = post[(size_t)k * 4  + (col - 4)];
        else if (col < 24) v = res [(size_t)k * 16 + (col - 8)];
        else               v = 0.f;
        sv[j] = (unsigned short)f2bf(v);
    }
    uint4 o;
    o.x = (unsigned)sv[0] | ((unsigned)sv[1] << 16);
    o.y = (unsigned)sv[2] | ((unsigned)sv[3] << 16);
    o.z = (unsigned)sv[4] | ((unsigned)sv[5] << 16);
    o.w = (unsigned)sv[6] | ((unsigned)sv[7] << 16);
    ws[((size_t)s * 2 + n) * 64 + lane] = o;
}

template<bool USE_WS>
__global__ __launch_bounds__(T, 4)
void mhc_mfma(const float* __restrict__ x,
              const float* __restrict__ phi_pre,
              const float* __restrict__ phi_post,
              const float* __restrict__ phi_res,
              const float* __restrict__ alpha_pre_p,
              const float* __restrict__ alpha_post_p,
              const float* __restrict__ alpha_res_p,
              const float* __restrict__ b_pre,
              const float* __restrict__ b_post,
              const float* __restrict__ b_res,
              const uint4* __restrict__ bws,
              float* __restrict__ out)
{
    __shared__ float sacc[WAVES][16][32];   // 16 KiB
    __shared__ float sssq[WAVES][16];
    __shared__ float smxq[WAVES][16];

    const int tid  = (int)threadIdx.x;
    const int wave = tid >> 6;
    const int lane = tid & 63;
    const int arow = lane & 15;             // A row within tile (== D col index)
    const int g    = lane >> 4;             // k-group
    const int row_base = (int)blockIdx.x * RPB;
    const float* __restrict__ xp = x + (size_t)(row_base + arow) * D_ + g * 8;

    f32x4 acc0 = {0.f, 0.f, 0.f, 0.f};
    f32x4 acc1 = {0.f, 0.f, 0.f, 0.f};
    float ssq = 0.f, mxq = 0.f;
    const int s0 = wave * SPW;

#pragma unroll 2
    for (int s = 0; s < SPW; ++s) {
        const int gs = s0 + s;
        const int k0 = gs * 32;
        const float4 a0 = *(const float4*)(xp + k0);
        const float4 a1 = *(const float4*)(xp + k0 + 4);

        bf16x8 bf0, bf1;
        if constexpr (USE_WS) {
            const uint4 b0 = bws[((size_t)gs * 2 + 0) * 64 + lane];
            const uint4 b1 = bws[((size_t)gs * 2 + 1) * 64 + lane];
            __builtin_memcpy(&bf0, &b0, 16);
            __builtin_memcpy(&bf1, &b1, 16);
        } else {
            const int colc = lane & 15;
#pragma unroll
            for (int n = 0; n < 2; ++n) {
                const int col = n * 16 + colc;
                unsigned short sv[8];
#pragma unroll
                for (int j = 0; j < 8; ++j) {
                    const int k = k0 + g * 8 + j;
                    float v;
                    if      (col < 4)  v = phi_pre [(size_t)k * 4  + col];
                    else if (col < 8)  v = phi_post[(size_t)k * 4  + (col - 4)];
                    else if (col < 24) v = phi_res [(size_t)k * 16 + (col - 8)];
                    else               v = 0.f;
                    sv[j] = (unsigned short)f2bf(v);
                }
                uint4 o;
                o.x = (unsigned)sv[0] | ((unsigned)sv[1] << 16);
                o.y = (unsigned)sv[2] | ((unsigned)sv[3] << 16);
                o.z = (unsigned)sv[4] | ((unsigned)sv[5] << 16);
                o.w = (unsigned)sv[6] | ((unsigned)sv[7] << 16);
                if (n == 0) __builtin_memcpy(&bf0, &o, 16);
                else        __builtin_memcpy(&bf1, &o, 16);
            }
        }

        ssq = fmaf(a0.x, a0.x, ssq); ssq = fmaf(a0.y, a0.y, ssq);
        ssq = fmaf(a0.z, a0.z, ssq); ssq = fmaf(a0.w, a0.w, ssq);
        ssq = fmaf(a1.x, a1.x, ssq); ssq = fmaf(a1.y, a1.y, ssq);
        ssq = fmaf(a1.z, a1.z, ssq); ssq = fmaf(a1.w, a1.w, ssq);
        mxq = fmaxf(mxq, fmaxf(fmaxf(a0.x*a0.x, a0.y*a0.y), fmaxf(a0.z*a0.z, a0.w*a0.w)));
        mxq = fmaxf(mxq, fmaxf(fmaxf(a1.x*a1.x, a1.y*a1.y), fmaxf(a1.z*a1.z, a1.w*a1.w)));

        bf16x8 af;
        af[0] = f2bf(a0.x); af[1] = f2bf(a0.y); af[2] = f2bf(a0.z); af[3] = f2bf(a0.w);
        af[4] = f2bf(a1.x); af[5] = f2bf(a1.y); af[6] = f2bf(a1.z); af[7] = f2bf(a1.w);

        acc0 = __builtin_amdgcn_mfma_f32_16x16x32_bf16(af, bf0, acc0, 0, 0, 0);
        acc1 = __builtin_amdgcn_mfma_f32_16x16x32_bf16(af, bf1, acc1, 0, 0, 0);
    }

    // ---- per-wave ssq/mxq reduce (lanes l, l^16, l^32, l^48 share a row) ----
    ssq += __shfl_xor(ssq, 16); ssq += __shfl_xor(ssq, 32);
    mxq = fmaxf(mxq, __shfl_xor(mxq, 16)); mxq = fmaxf(mxq, __shfl_xor(mxq, 32));

    // ---- dump wave partials: D row = 4*g + reg, D col = lane&15 (+16 frag1) ----
#pragma unroll
    for (int r = 0; r < 4; ++r) {
        sacc[wave][g * 4 + r][arow]      = acc0[r];
        sacc[wave][g * 4 + r][16 + arow] = acc1[r];
    }
    if (lane < 16) { sssq[wave][arow] = ssq; smxq[wave][arow] = mxq; }
    __syncthreads();

    // ---- cross-wave reduce + epilogue: thread t = erow*32 + el ----
    const int erow = tid >> 5;
    const int el   = tid & 31;
    const int orow = row_base + erow;

    float redv = 0.f;
    if (el < 24) {
#pragma unroll
        for (int w = 0; w < WAVES; ++w) redv += sacc[w][erow][el];
    } else if (el == 24) {
#pragma unroll
        for (int w = 0; w < WAVES; ++w) redv += sssq[w][erow];
    }
    float mxrow = smxq[0][erow];
#pragma unroll
    for (int w = 1; w < WAVES; ++w) mxrow = fmaxf(mxrow, smxq[w][erow]);

    const float ssq_tot = __shfl(redv, 24, 32);
    const float msq  = ssq_tot * (1.f / 8192.f) + 1e-6f;
    const float rinv = 1.f / sqrtf(msq);

    const float a_pre  = alpha_pre_p[0];
    const float a_post = alpha_post_p[0];
    const float a_res  = alpha_res_p[0];

    const bool needclamp = (mxrow > 100.f * msq);

    if (!needclamp) {
        const int e = el & 15;
        float m = __shfl(redv, 8 + e, 32);
        m = a_res * m * rinv + b_res[e];
        m = fminf(fmaxf(m, -20.f), 20.f);
        m = expf(m);
        for (int it = 0; it < 20; ++it) {
            float rs = m + __shfl_xor(m, 1);
            rs += __shfl_xor(rs, 2);
            m = m / (rs + 1e-6f);
            float cs = m + __shfl_xor(m, 4);
            cs += __shfl_xor(cs, 8);
            m = m / (cs + 1e-6f);
        }
        if (el < 16)
            out[OFF_RES + (size_t)orow * 16 + el] = m;
        if (el < 4) {
            const float h = a_pre * redv * rinv + b_pre[el];
            out[(size_t)orow * 4 + el] = 1.f / (1.f + expf(-h));
        } else if (el < 8) {
            const float h = a_post * redv * rinv + b_post[el - 4];
            out[OFF_POST + (size_t)orow * 4 + (el - 4)] = 2.f / (1.f + expf(-h));
        }
    } else if (el == 0) {
        // exact clamped fp32 slow path — semantically required, never expected
        const float* __restrict__ xrow = x + (size_t)orow * D_;
        float dp[4] = {0.f,0.f,0.f,0.f}, dq[4] = {0.f,0.f,0.f,0.f};
        float dr[16] = {0.f,0.f,0.f,0.f,0.f,0.f,0.f,0.f,
                        0.f,0.f,0.f,0.f,0.f,0.f,0.f,0.f};
        for (int k = 0; k < D_; ++k) {
            float v = xrow[k] * rinv;
            v = fminf(fmaxf(v, -10.f), 10.f);
            const float4 pp = *(const float4*)(phi_pre  + (size_t)k * 4);
            const float4 pq = *(const float4*)(phi_post + (size_t)k * 4);
            dp[0] = fmaf(v, pp.x, dp[0]); dp[1] = fmaf(v, pp.y, dp[1]);
            dp[2] = fmaf(v, pp.z, dp[2]); dp[3] = fmaf(v, pp.w, dp[3]);
            dq[0] = fmaf(v, pq.x, dq[0]); dq[1] = fmaf(v, pq.y, dq[1]);
            dq[2] = fmaf(v, pq.z, dq[2]); dq[3] = fmaf(v, pq.w, dq[3]);
#pragma unroll
            for (int j2 = 0; j2 < 4; ++j2) {
                const float4 pr = *(const float4*)(phi_res + (size_t)k * 16 + 4 * j2);
                dr[4*j2+0] = fmaf(v, pr.x, dr[4*j2+0]);
                dr[4*j2+1] = fmaf(v, pr.y, dr[4*j2+1]);
                dr[4*j2+2] = fmaf(v, pr.z, dr[4*j2+2]);
                dr[4*j2+3] = fmaf(v, pr.w, dr[4*j2+3]);
            }
        }
        float mm[16];
#pragma unroll
        for (int e2 = 0; e2 < 16; ++e2) {
            float m = a_res * dr[e2] + b_res[e2];
            m = fminf(fmaxf(m, -20.f), 20.f);
            mm[e2] = expf(m);
        }
        for (int it = 0; it < 20; ++it) {
#pragma unroll
            for (int i2 = 0; i2 < 4; ++i2) {
                const float rs = mm[i2*4] + mm[i2*4+1] + mm[i2*4+2] + mm[i2*4+3] + 1e-6f;
#pragma unroll
                for (int j2 = 0; j2 < 4; ++j2) mm[i2*4+j2] /= rs;
            }
#pragma unroll
            for (int j2 = 0; j2 < 4; ++j2) {
                const float cs = mm[j2] + mm[4+j2] + mm[8+j2] + mm[12+j2] + 1e-6f;
#pragma unroll
                for (int i2 = 0; i2 < 4; ++i2) mm[i2*4+j2] /= cs;
            }
        }
#pragma unroll
        for (int j = 0; j < 4; ++j) {
            out[(size_t)orow * 4 + j]            = 1.f / (1.f + expf(-(a_pre  * dp[j] + b_pre[j])));
            out[OFF_POST + (size_t)orow * 4 + j] = 2.f / (1.f + expf(-(a_post * dq[j] + b_post[j])));
        }
#pragma unroll
        for (int e2 = 0; e2 < 16; ++e2)
            out[OFF_RES + (size_t)orow * 16 + e2] = mm[e2];
    }
}

extern "C" void kernel_launch(void* const* d_in, const int* in_sizes, int n_in,
                              void* d_out, int out_size, void* d_ws, size_t ws_size,
                              hipStream_t stream)
{
    const float* x        = (const float*)d_in[0];
    const float* phi_pre  = (const float*)d_in[1];
    const float* phi_post = (const float*)d_in[2];
    const float* phi_res  = (const float*)d_in[3];
    const float* a_pre    = (const float*)d_in[4];
    const float* a_post   = (const float*)d_in[5];
    const float* a_res    = (const float*)d_in[6];
    const float* b_pre    = (const float*)d_in[7];
    const float* b_post   = (const float*)d_in[8];
    const float* b_res    = (const float*)d_in[9];
    float* out = (float*)d_out;

    const bool use_ws = (ws_size >= WS_NEED) && (d_ws != nullptr);
    dim3 grid(NROWS / RPB);   // 512
    dim3 block(T);            // 512

    if (use_ws) {
        uint4* ws = (uint4*)d_ws;
        hipLaunchKernelGGL(prep_bfrag, dim3(KSTEPS * 2 * 64 / 256), dim3(256), 0, stream,
                           phi_pre, phi_post, phi_res, ws);
        hipLaunchKernelGGL((mhc_mfma<true>), grid, block, 0, stream,
                           x, phi_pre, phi_post, phi_res,
                           a_pre, a_post, a_res, b_pre, b_post, b_res,
                           (const uint4*)ws, out);
    } else {
        hipLaunchKernelGGL((mhc_mfma<false>), grid, block, 0, stream,
                           x, phi_pre, phi_post, phi_res,
                           a_pre, a_post, a_res, b_pre, b_post, b_res,
                           (const uint4*)nullptr, out);
    }
}